// Round 18
// baseline (15.184 us; speedup 1.0000x reference)
//
#include <hip/hip_runtime.h>
#include <hip/hip_bf16.h>
#include <math.h>

#define N 2048
#define CIN 128
#define COUT 64
#define NEG 0.2f
#define JB 16              // j-rows per attn block
#define NJB (N / JB)       // 128 j-blocks; x2 channel halves = 256 blocks

typedef __attribute__((ext_vector_type(8))) short short8;   // 8 bf16
typedef __attribute__((ext_vector_type(4))) float f32x4;

__device__ __forceinline__ ushort bf16u(float x) {
  __hip_bfloat16 b = __float2bfloat16(x);
  return *reinterpret_cast<ushort*>(&b);
}
__device__ __forceinline__ uint pack2(float lo, float hi) {
  return (uint)bf16u(lo) | ((uint)bf16u(hi) << 16);
}

// Kernel 1: slim MFMA gemm (R13 structure). a_s/a_d are PRESCALED by
// log2(e) so the attn kernel can use exp2 (bare v_exp_f32) — valid since
// leaky_relu is positively homogeneous: lrelu(c*x) = c*lrelu(x) for c>0.
__global__ __launch_bounds__(256) void gat_gemm_mfma(
    const float* __restrict__ data, const float* __restrict__ W,
    const float* __restrict__ att_src, const float* __restrict__ att_dst,
    ushort* __restrict__ hfrag, float* __restrict__ a_s,
    float* __restrict__ a_d) {
  const int tid = (int)threadIdx.x;
  const int ci = tid >> 6;            // wave = output col-tile
  const int lane = tid & 63;
  const int i0 = (int)blockIdx.x * 16;
  const int q = lane >> 4;            // k-subgroup / C-row group
  const int n15 = lane & 15;
  const int mrow = i0 + n15;          // A-frag row for this lane

  short8 af[4];
#pragma unroll
  for (int kc = 0; kc < 4; ++kc) {
    const int col = kc * 32 + q * 8;
    const float4 f0 = *(const float4*)&data[mrow * CIN + col];
    const float4 f1 = *(const float4*)&data[mrow * CIN + col + 4];
    uint4 pa;
    pa.x = pack2(f0.x, f0.y);
    pa.y = pack2(f0.z, f0.w);
    pa.z = pack2(f1.x, f1.y);
    pa.w = pack2(f1.z, f1.w);
    af[kc] = *(short8*)&pa;
  }

  const int cg = ci * 16 + n15;
  f32x4 acc = {0.f, 0.f, 0.f, 0.f};
#pragma unroll
  for (int kc = 0; kc < 4; ++kc) {
    const int kr = kc * 32 + q * 8;
    ushort uw[8];
#pragma unroll
    for (int e = 0; e < 8; ++e) uw[e] = bf16u(W[(kr + e) * COUT + cg]);
    uint4 pw;
    pw.x = (uint)uw[0] | ((uint)uw[1] << 16);
    pw.y = (uint)uw[2] | ((uint)uw[3] << 16);
    pw.z = (uint)uw[4] | ((uint)uw[5] << 16);
    pw.w = (uint)uw[6] | ((uint)uw[7] << 16);
    acc = __builtin_amdgcn_mfma_f32_16x16x32_bf16(af[kc], *(short8*)&pw,
                                                  acc, 0, 0, 0);
  }

  // hfrag store: verified B-frag order (R8..R17 on-device)
  {
    const int ib = i0 + q * 4;
    const int f = (ib >> 5) * 4 + ci;
    const int lp = ((ib >> 3) & 3) * 16 + n15;
    uint2 hv;
    hv.x = pack2(acc[0], acc[1]);
    hv.y = pack2(acc[2], acc[3]);
    *(uint2*)&hfrag[((size_t)(f * 64 + lp) << 3) + (ib & 7)] = hv;
  }

  __shared__ float asp[4][16];
  __shared__ float adp[4][16];
  {
    const float sc = att_src[cg] * 1.44269504088896f;  // log2(e) prescale
    const float dc = att_dst[cg] * 1.44269504088896f;
    float ps[4], pd[4];
#pragma unroll
    for (int r = 0; r < 4; ++r) { ps[r] = acc[r] * sc; pd[r] = acc[r] * dc; }
#pragma unroll
    for (int off = 1; off < 16; off <<= 1) {
#pragma unroll
      for (int r = 0; r < 4; ++r) {
        ps[r] += __shfl_xor(ps[r], off);
        pd[r] += __shfl_xor(pd[r], off);
      }
    }
    if (n15 == 0) {
#pragma unroll
      for (int r = 0; r < 4; ++r) {
        asp[ci][q * 4 + r] = ps[r];
        adp[ci][q * 4 + r] = pd[r];
      }
    }
  }
  __syncthreads();
  if (tid < 16) {
    a_s[i0 + tid] = asp[0][tid] + asp[1][tid] + asp[2][tid] + asp[3][tid];
    a_d[i0 + tid] = adp[0][tid] + adp[1][tid] + adp[2][tid] + adp[3][tid];
  }
}

// Kernel 2: flash triangular MFMA attention, channel-half split (R17).
// Interior K-steps skip the causal mask (wave-uniform: only ks==nks-1 can
// mask — interior max-i = 32*(nks-1)-1 < j0 for both bj parities).
// Weights via exp2 of prescaled logits (one v_exp, no mul).
__global__ __launch_bounds__(1024) void gat_attn_flash(
    const ushort* __restrict__ hfrag, const float* __restrict__ a_s,
    const float* __restrict__ a_d, const float* __restrict__ bias,
    float* __restrict__ out) {
  const int b = (int)blockIdx.x;
  const int bj = NJB - 1 - (b >> 1);          // heavy j-blocks first
  const int chalf = b & 1;                    // channel half 0/1
  const int tid = (int)threadIdx.x;
  const int wid = tid >> 6;                   // 0..15
  const int lane = tid & 63;
  const int j0 = bj * JB;
  const int jme = j0 + (lane & 15);
  const int kgrp = lane >> 4;
  const float ad_me = a_d[jme];               // prescaled by log2(e)
  const int nks = (bj + 2) >> 1;              // K=32 steps covering i<=j0+15

  f32x4 acc0 = {0.f, 0.f, 0.f, 0.f};
  f32x4 acc1 = acc0;
  float dsum = 0.f;
  const uint4* hf = (const uint4*)hfrag;

  for (int ks = wid; ks < nks; ks += 16) {
    const int ibase = ks * 32 + kgrp * 8;
    const float4 asa = *(const float4*)&a_s[ibase];
    const float4 asb = *(const float4*)&a_s[ibase + 4];
    const float av[8] = {asa.x, asa.y, asa.z, asa.w,
                         asb.x, asb.y, asb.z, asb.w};
    short8 afw;
    if (ks != nks - 1) {                      // interior step: no mask
#pragma unroll
      for (int e = 0; e < 8; ++e) {
        float x = av[e] + ad_me;
        x = fmaxf(x, NEG * x);                // leaky_relu (homogeneous)
        const float wgt = exp2f(x);           // bare v_exp_f32
        dsum += wgt;
        afw[e] = (short)bf16u(wgt);
      }
    } else {                                  // diagonal step: causal mask
#pragma unroll
      for (int e = 0; e < 8; ++e) {
        float x = av[e] + ad_me;
        x = fmaxf(x, NEG * x);
        float wgt = exp2f(x);
        if (ibase + e > jme) wgt = 0.f;       // i <= j
        dsum += wgt;
        afw[e] = (short)bf16u(wgt);
      }
    }
    const int fbase = (ks * 4 + chalf * 2) * 64 + lane;
    const uint4 b0 = hf[fbase];
    const uint4 b1 = hf[fbase + 64];
    acc0 = __builtin_amdgcn_mfma_f32_16x16x32_bf16(afw, *(const short8*)&b0,
                                                   acc0, 0, 0, 0);
    acc1 = __builtin_amdgcn_mfma_f32_16x16x32_bf16(afw, *(const short8*)&b1,
                                                   acc1, 0, 0, 0);
  }

  // den over the 4 k-chunks within the wave (identical in both halves)
  dsum += __shfl_xor(dsum, 16);
  dsum += __shfl_xor(dsum, 32);

  __shared__ float rbuf[8][16][64];    // [t16*4+r][wid][lane] (32KB)
  __shared__ float dbuf[16][16];       // [wid][j]
#pragma unroll
  for (int r = 0; r < 4; ++r) {
    rbuf[r][wid][lane]     = acc0[r];
    rbuf[4 + r][wid][lane] = acc1[r];
  }
  if (lane < 16) dbuf[wid][lane] = dsum;
  __syncthreads();

  // epilogue: 512 outputs (16j x 32c); thread tid<512 handles one
  if (tid < 512) {
    const int j = tid >> 5, cl = tid & 31;
    const int qq = j >> 2, rr = j & 3, t16 = cl >> 4, n = cl & 15;
    float num = 0.f, den = 0.f;
#pragma unroll
    for (int ww = 0; ww < 16; ++ww) {
      num += rbuf[t16 * 4 + rr][ww][qq * 16 + n];
      den += dbuf[ww][j];
    }
    const int cg = chalf * 32 + cl;
    const float v = num / den + bias[cg];
    out[(size_t)(j0 + j) * COUT + cg] = v > 0.f ? v : 0.f;
  }
}

extern "C" void kernel_launch(void* const* d_in, const int* in_sizes, int n_in,
                              void* d_out, int out_size, void* d_ws, size_t ws_size,
                              hipStream_t stream) {
  const float* data    = (const float*)d_in[0];  // [N, CIN]
  const float* W       = (const float*)d_in[1];  // [CIN, COUT]
  const float* att_src = (const float*)d_in[2];  // [COUT]
  const float* att_dst = (const float*)d_in[3];  // [COUT]
  const float* bias    = (const float*)d_in[4];  // [COUT]
  float* out = (float*)d_out;                    // [N, COUT]

  ushort* hfrag = (ushort*)d_ws;                 // N*COUT bf16 (256KB)
  float* a_s  = (float*)d_ws + 65536;            // N (prescaled by log2 e)
  float* a_d  = a_s + N;                         // N (prescaled by log2 e)

  gat_gemm_mfma<<<N / 16, 256, 0, stream>>>(data, W, att_src, att_dst,
                                            hfrag, a_s, a_d);
  gat_attn_flash<<<NJB * 2, 1024, 0, stream>>>(hfrag, a_s, a_d, bias, out);
}

// Round 19
// 14.602 us; speedup vs baseline: 1.0398x; 1.0398x over previous
//
#include <hip/hip_runtime.h>
#include <hip/hip_bf16.h>
#include <math.h>

#define N 2048
#define CIN 128
#define COUT 64
#define NEG 0.2f
#define JB 16              // j-rows per attn block
#define NJB (N / JB)       // 128 j-blocks; x2 channel halves = 256 blocks

typedef __attribute__((ext_vector_type(8))) short short8;   // 8 bf16
typedef __attribute__((ext_vector_type(4))) float f32x4;

__device__ __forceinline__ ushort bf16u(float x) {
  __hip_bfloat16 b = __float2bfloat16(x);
  return *reinterpret_cast<ushort*>(&b);
}
__device__ __forceinline__ uint pack2(float lo, float hi) {
  return (uint)bf16u(lo) | ((uint)bf16u(hi) << 16);
}

// Kernel 1: slim MFMA gemm (R13, measured best). 128 blocks x 256 threads;
// block = 16-row tile; wave ci owns output cols [ci*16, ci*16+16).
// All 4 waves share the tile's A-frags -> load/pack A global->reg (no LDS,
// no barrier on the MFMA path).
__global__ __launch_bounds__(256) void gat_gemm_mfma(
    const float* __restrict__ data, const float* __restrict__ W,
    const float* __restrict__ att_src, const float* __restrict__ att_dst,
    ushort* __restrict__ hfrag, float* __restrict__ a_s,
    float* __restrict__ a_d) {
  const int tid = (int)threadIdx.x;
  const int ci = tid >> 6;            // wave = output col-tile
  const int lane = tid & 63;
  const int i0 = (int)blockIdx.x * 16;
  const int q = lane >> 4;            // k-subgroup / C-row group
  const int n15 = lane & 15;
  const int mrow = i0 + n15;          // A-frag row for this lane

  // A-frags: af[kc][e] = bf16(data[mrow][kc*32 + q*8 + e])
  short8 af[4];
#pragma unroll
  for (int kc = 0; kc < 4; ++kc) {
    const int col = kc * 32 + q * 8;
    const float4 f0 = *(const float4*)&data[mrow * CIN + col];
    const float4 f1 = *(const float4*)&data[mrow * CIN + col + 4];
    uint4 pa;
    pa.x = pack2(f0.x, f0.y);
    pa.y = pack2(f0.z, f0.w);
    pa.z = pack2(f1.x, f1.y);
    pa.w = pack2(f1.z, f1.w);
    af[kc] = *(short8*)&pa;
  }

  // B-frags + MFMA: bf[kc][e] = bf16(W[kc*32 + q*8 + e][ci*16 + n15])
  const int cg = ci * 16 + n15;
  f32x4 acc = {0.f, 0.f, 0.f, 0.f};
#pragma unroll
  for (int kc = 0; kc < 4; ++kc) {
    const int kr = kc * 32 + q * 8;
    ushort uw[8];
#pragma unroll
    for (int e = 0; e < 8; ++e) uw[e] = bf16u(W[(kr + e) * COUT + cg]);
    uint4 pw;
    pw.x = (uint)uw[0] | ((uint)uw[1] << 16);
    pw.y = (uint)uw[2] | ((uint)uw[3] << 16);
    pw.z = (uint)uw[4] | ((uint)uw[5] << 16);
    pw.w = (uint)uw[6] | ((uint)uw[7] << 16);
    acc = __builtin_amdgcn_mfma_f32_16x16x32_bf16(af[kc], *(short8*)&pw,
                                                  acc, 0, 0, 0);
  }

  // hfrag store: verified B-frag order (R8..R17 on-device)
  {
    const int ib = i0 + q * 4;
    const int f = (ib >> 5) * 4 + ci;
    const int lp = ((ib >> 3) & 3) * 16 + n15;
    uint2 hv;
    hv.x = pack2(acc[0], acc[1]);
    hv.y = pack2(acc[2], acc[3]);
    *(uint2*)&hfrag[((size_t)(f * 64 + lp) << 3) + (ib & 7)] = hv;
  }

  // a_s/a_d: per-wave 16-lane shuffle tree + tiny LDS cross-wave sum
  __shared__ float asp[4][16];
  __shared__ float adp[4][16];
  {
    const float sc = att_src[cg];
    const float dc = att_dst[cg];
    float ps[4], pd[4];
#pragma unroll
    for (int r = 0; r < 4; ++r) { ps[r] = acc[r] * sc; pd[r] = acc[r] * dc; }
#pragma unroll
    for (int off = 1; off < 16; off <<= 1) {
#pragma unroll
      for (int r = 0; r < 4; ++r) {
        ps[r] += __shfl_xor(ps[r], off);
        pd[r] += __shfl_xor(pd[r], off);
      }
    }
    if (n15 == 0) {
#pragma unroll
      for (int r = 0; r < 4; ++r) {
        asp[ci][q * 4 + r] = ps[r];
        adp[ci][q * 4 + r] = pd[r];
      }
    }
  }
  __syncthreads();
  if (tid < 16) {
    a_s[i0 + tid] = asp[0][tid] + asp[1][tid] + asp[2][tid] + asp[3][tid];
    a_d[i0 + tid] = adp[0][tid] + adp[1][tid] + adp[2][tid] + adp[3][tid];
  }
}

// Kernel 2: flash triangular MFMA attention, split by output-channel half
// (R17, measured best). 256 blocks x 1024 threads: block (bj, chalf)
// computes channels [chalf*32, chalf*32+32) of j-rows [bj*16, +16).
// Per K-step: 2 hfrag loads + 8 exp (redundant across halves, VALU-cheap,
// hidden under MFMA/loads) + 2 MFMA. All 256 CUs get a block.
__global__ __launch_bounds__(1024) void gat_attn_flash(
    const ushort* __restrict__ hfrag, const float* __restrict__ a_s,
    const float* __restrict__ a_d, const float* __restrict__ bias,
    float* __restrict__ out) {
  const int b = (int)blockIdx.x;
  const int bj = NJB - 1 - (b >> 1);          // heavy j-blocks first
  const int chalf = b & 1;                    // channel half 0/1
  const int tid = (int)threadIdx.x;
  const int wid = tid >> 6;                   // 0..15
  const int lane = tid & 63;
  const int j0 = bj * JB;
  const int jme = j0 + (lane & 15);
  const int kgrp = lane >> 4;
  const float ad_me = a_d[jme];
  const int nks = (bj + 2) >> 1;              // K=32 steps covering i<=j0+15

  f32x4 acc0 = {0.f, 0.f, 0.f, 0.f};
  f32x4 acc1 = acc0;
  float dsum = 0.f;
  const uint4* hf = (const uint4*)hfrag;

  for (int ks = wid; ks < nks; ks += 16) {
    const int ibase = ks * 32 + kgrp * 8;
    const float4 asa = *(const float4*)&a_s[ibase];
    const float4 asb = *(const float4*)&a_s[ibase + 4];
    const float av[8] = {asa.x, asa.y, asa.z, asa.w,
                         asb.x, asb.y, asb.z, asb.w};
    short8 afw;
#pragma unroll
    for (int e = 0; e < 8; ++e) {
      float x = av[e] + ad_me;
      x = fmaxf(x, NEG * x);                  // leaky_relu
      float wgt = __expf(x);                  // no max-shift (logits bounded)
      if (ibase + e > jme) wgt = 0.f;         // causal mask i <= j
      dsum += wgt;
      afw[e] = (short)bf16u(wgt);
    }
    const int fbase = (ks * 4 + chalf * 2) * 64 + lane;
    const uint4 b0 = hf[fbase];
    const uint4 b1 = hf[fbase + 64];
    acc0 = __builtin_amdgcn_mfma_f32_16x16x32_bf16(afw, *(const short8*)&b0,
                                                   acc0, 0, 0, 0);
    acc1 = __builtin_amdgcn_mfma_f32_16x16x32_bf16(afw, *(const short8*)&b1,
                                                   acc1, 0, 0, 0);
  }

  // den over the 4 k-chunks within the wave (identical in both halves)
  dsum += __shfl_xor(dsum, 16);
  dsum += __shfl_xor(dsum, 32);

  __shared__ float rbuf[8][16][64];    // [t16*4+r][wid][lane] (32KB)
  __shared__ float dbuf[16][16];       // [wid][j]
#pragma unroll
  for (int r = 0; r < 4; ++r) {
    rbuf[r][wid][lane]     = acc0[r];
    rbuf[4 + r][wid][lane] = acc1[r];
  }
  if (lane < 16) dbuf[wid][lane] = dsum;
  __syncthreads();

  // epilogue: 512 outputs (16j x 32c); thread tid<512 handles one
  if (tid < 512) {
    const int j = tid >> 5, cl = tid & 31;
    const int qq = j >> 2, rr = j & 3, t16 = cl >> 4, n = cl & 15;
    float num = 0.f, den = 0.f;
#pragma unroll
    for (int ww = 0; ww < 16; ++ww) {
      num += rbuf[t16 * 4 + rr][ww][qq * 16 + n];
      den += dbuf[ww][j];
    }
    const int cg = chalf * 32 + cl;
    const float v = num / den + bias[cg];
    out[(size_t)(j0 + j) * COUT + cg] = v > 0.f ? v : 0.f;
  }
}

extern "C" void kernel_launch(void* const* d_in, const int* in_sizes, int n_in,
                              void* d_out, int out_size, void* d_ws, size_t ws_size,
                              hipStream_t stream) {
  const float* data    = (const float*)d_in[0];  // [N, CIN]
  const float* W       = (const float*)d_in[1];  // [CIN, COUT]
  const float* att_src = (const float*)d_in[2];  // [COUT]
  const float* att_dst = (const float*)d_in[3];  // [COUT]
  const float* bias    = (const float*)d_in[4];  // [COUT]
  float* out = (float*)d_out;                    // [N, COUT]

  ushort* hfrag = (ushort*)d_ws;                 // N*COUT bf16 (256KB)
  float* a_s  = (float*)d_ws + 65536;            // N
  float* a_d  = a_s + N;                         // N

  gat_gemm_mfma<<<N / 16, 256, 0, stream>>>(data, W, att_src, att_dst,
                                            hfrag, a_s, a_d);
  gat_attn_flash<<<NJB * 2, 1024, 0, stream>>>(hfrag, a_s, a_d, bias, out);
}